// Round 6
// baseline (539.554 us; speedup 1.0000x reference)
//
#include <hip/hip_runtime.h>
#include <hip/hip_bf16.h>
#include <cstdint>
#include <cstddef>

#define B_   128
#define NCH  64
#define T_   30720
#define EPSF 1e-12f
#define THRF 0.5f

typedef float  f32x4 __attribute__((ext_vector_type(4)));
typedef short  s16x8 __attribute__((ext_vector_type(8)));
typedef unsigned short u16;

static __device__ __forceinline__ short bf16s(float f) {
    return (short)__builtin_bit_cast(u16, __float2bfloat16(f));
}

// Upper-triangle fragment list (i <= j), 10 of 16 blocks of the 64x64 Gram.
static constexpr int FI[10] = {0,0,0,0,1,1,1,2,2,3};
static constexpr int FJ[10] = {0,1,2,3,1,2,3,2,3,3};

// ---------------------------------------------------------------------------
// Stage 1 (LDS-free data path): per (batch, T-chunk) block of 4 independent
// waves. Wave w owns t-range [w*Tc/4, (w+1)*Tc/4), iterating K-steps of 32.
// Per K-step: the MFMA bf16 A/B fragment is "8 contiguous t-samples of one
// channel per lane" == one 32B contiguous global load. So: load fragments
// HBM->VGPR (issued one step early), NT-store the same registers to out_x
// (fused exactly-once copy), cvt f32->bf16 in-register, 10 MFMA for the
// upper triangle of P = X X^T. No LDS, no barriers in the main loop.
// Epilogue: one barrier; merge 4 waves' partial Grams + S sums via LDS.
// bf16 corr error <= ~4e-3, 40x under the 0.108 absmax threshold.
// ---------------------------------------------------------------------------
__global__ __launch_bounds__(256) void corr_stage1(
    const float* __restrict__ x, float* __restrict__ out_x,
    float* __restrict__ P, float* __restrict__ S,
    int split, int Tc)
{
    __shared__ float mbuf[4][2560];   // 40 KB: 4 waves x 10 frags x 256
    __shared__ float sbuf[4][64];     // per-wave channel sums

    const int tid  = threadIdx.x;
    const int lane = tid & 63;
    const int w    = tid >> 6;          // wave 0..3
    const int cc   = lane & 15;         // fragment row/col within block
    const int g    = lane >> 4;         // k-group: this lane's 8 t-samples

    const int bid = blockIdx.x;
    const int b   = bid / split;
    const int c   = bid - b * split;

    const int NK  = Tc >> 7;            // K-steps per wave (Tc/4/32), even
    const int tw0 = w * (Tc >> 2);      // wave's t-offset within chunk

    const size_t base = (size_t)b * ((size_t)NCH * T_) + (size_t)c * Tc
                      + (size_t)tw0 + (size_t)(g * 8);
    const float* xw = x + base;
    float*       ow = out_x + base;

    f32x4 acc[10];
    #pragma unroll
    for (int f = 0; f < 10; ++f) acc[f] = (f32x4)(0.f);
    float ssum[4] = {0.f, 0.f, 0.f, 0.f};

    f32x4 L0[4], H0[4], L1[4], H1[4];   // two K-steps in flight

    auto ISSUE = [&](int s, f32x4* L, f32x4* H) {
        const int toff = s * 32;
        #pragma unroll
        for (int i = 0; i < 4; ++i) {
            const float* p = xw + (size_t)(i * 16 + cc) * T_ + toff;
            L[i] = *reinterpret_cast<const f32x4*>(p);
            H[i] = *reinterpret_cast<const f32x4*>(p + 4);
        }
    };
    auto CONSUME = [&](int s, f32x4* L, f32x4* H) {
        const int toff = s * 32;
        s16x8 A[4];
        #pragma unroll
        for (int i = 0; i < 4; ++i) {
            float* q = ow + (size_t)(i * 16 + cc) * T_ + toff;
            __builtin_nontemporal_store(L[i], reinterpret_cast<f32x4*>(q));
            __builtin_nontemporal_store(H[i], reinterpret_cast<f32x4*>(q + 4));
            ssum[i] += ((L[i].x + L[i].y) + (L[i].z + L[i].w))
                     + ((H[i].x + H[i].y) + (H[i].z + H[i].w));
            A[i][0] = bf16s(L[i].x); A[i][1] = bf16s(L[i].y);
            A[i][2] = bf16s(L[i].z); A[i][3] = bf16s(L[i].w);
            A[i][4] = bf16s(H[i].x); A[i][5] = bf16s(H[i].y);
            A[i][6] = bf16s(H[i].z); A[i][7] = bf16s(H[i].w);
        }
        #pragma unroll
        for (int f = 0; f < 10; ++f)
            acc[f] = __builtin_amdgcn_mfma_f32_16x16x32_bf16(
                A[FI[f]], A[FJ[f]], acc[f], 0, 0, 0);
    };

    ISSUE(0, L0, H0);
    ISSUE(1, L1, H1);
    for (int s = 0; s < NK; s += 2) {
        CONSUME(s, L0, H0);
        if (s + 2 < NK) ISSUE(s + 2, L0, H0);
        CONSUME(s + 1, L1, H1);
        if (s + 3 < NK) ISSUE(s + 3, L1, H1);
    }

    // ---- per-wave S reduce over k-groups (butterfly over lane bits 4,5) ----
    #pragma unroll
    for (int i = 0; i < 4; ++i) {
        ssum[i] += __shfl_xor(ssum[i], 16, 64);
        ssum[i] += __shfl_xor(ssum[i], 32, 64);
    }
    if (lane < 16) {
        #pragma unroll
        for (int i = 0; i < 4; ++i) sbuf[w][i * 16 + lane] = ssum[i];
    }

    // ---- stash wave-partial Gram fragments: [w][f*256 + lane*4 + reg] ----
    #pragma unroll
    for (int f = 0; f < 10; ++f)
        *reinterpret_cast<f32x4*>(&mbuf[w][f * 256 + lane * 4]) = acc[f];
    __syncthreads();

    // ---- merge 4 waves, expand triangle, write P ----
    float* Pc = P + ((size_t)bid << 12);
    const int l2  = tid >> 2;           // fragment lane
    const int rg  = tid & 3;            // fragment reg
    const int row = ((l2 >> 4) << 2) + rg;   // D layout: row=(lane>>4)*4+reg
    const int col = l2 & 15;                  //           col=lane&15
    #pragma unroll
    for (int f = 0; f < 10; ++f) {
        const int e = f * 256 + tid;
        const float v = mbuf[0][e] + mbuf[1][e] + mbuf[2][e] + mbuf[3][e];
        const int i = FI[f], j = FJ[f];
        Pc[(i * 16 + row) * 64 + (j * 16 + col)] = v;
        if (i != j)
            Pc[(j * 16 + col) * 64 + (i * 16 + row)] = v;
    }
    if (tid < NCH) {
        const float s = sbuf[0][tid] + sbuf[1][tid] + sbuf[2][tid] + sbuf[3][tid];
        S[(size_t)bid * NCH + tid] = s;
    }
}

// ---------------------------------------------------------------------------
// Stage 2: combine chunk partials -> corr -> threshold -> adj
// ---------------------------------------------------------------------------
__global__ __launch_bounds__(256) void corr_stage2(
    const float* __restrict__ P, const float* __restrict__ S,
    float* __restrict__ adj, int split)
{
    const int idx = blockIdx.x * 256 + threadIdx.x;   // < 128*4096
    const int b  = idx >> 12;
    const int nm = idx & 4095;
    const int n  = nm >> 6;
    const int m  = nm & 63;

    float G = 0.f, Gnn = 0.f, Gmm = 0.f, Sn = 0.f, Sm = 0.f;
    for (int c = 0; c < split; ++c) {
        const float* Pc = P + ((size_t)(b * split + c) << 12);
        const float* Sc = S + (size_t)(b * split + c) * NCH;
        G   += Pc[nm];
        Gnn += Pc[n * 65];
        Gmm += Pc[m * 65];
        Sn  += Sc[n];
        Sm  += Sc[m];
    }
    const float invT = 1.0f / (float)T_;
    const float cov  = G   - Sn * Sm * invT;
    const float vn   = Gnn - Sn * Sn * invT;
    const float vm   = Gmm - Sm * Sm * invT;
    const float den  = sqrtf(vn) * sqrtf(vm) + EPSF;
    float corr = cov / den;
    if (n == m) corr = 0.f;
    adj[idx] = (fabsf(corr) >= THRF) ? corr : 0.f;
}

// ---------------------------------------------------------------------------
extern "C" void kernel_launch(void* const* d_in, const int* in_sizes, int n_in,
                              void* d_out, int out_size, void* d_ws, size_t ws_size,
                              hipStream_t stream)
{
    const float* x   = (const float*)d_in[0];
    float* out   = (float*)d_out;
    float* adj   = out;                                  // 128*64*64
    float* out_x = out + (size_t)B_ * NCH * NCH;         // passthrough x

    // split must divide 240 with Tc divisible by 256 (NK even): 12 -> 6 -> 3
    int split = 12;
    while (split > 3 &&
           (size_t)B_ * split * (4096 + NCH) * sizeof(float) > ws_size)
        split >>= 1;

    float* P = (float*)d_ws;
    float* S = P + (size_t)B_ * split * 4096;
    const int Tc = T_ / split;

    corr_stage1<<<dim3(B_ * split), dim3(256), 0, stream>>>(x, out_x, P, S, split, Tc);
    corr_stage2<<<dim3((B_ * 4096) / 256), dim3(256), 0, stream>>>(P, S, adj, split);
}